// Round 8
// baseline (310.325 us; speedup 1.0000x reference)
//
#include <hip/hip_runtime.h>

// log-ODE Neural CDE. B=32 chains, 32 windows, Heun = 2 vector-field evals
// per window. fp32 in/out, f32 accum, f16 weights/activations.
// 512 threads/block (8 waves), one block per batch element.
//
// R17 = R12 base (verified 233us, VGPR 112, no spill) + MFMA for the two W2
// phases (B, E). Post-mortem R13-R16: allocator hard-caps 512-thr blocks at
// 128 VGPR and spills on live-set growth (R16: P[8] DPP interleave, WRITE
// 713KB); MfmaUtil has been 0.0 all session while ~59% of wall is VALU issue
// -> offload to the idle matrix pipe, REDUCING register demand:
//  * E is a real GEMM: D2 = W2 @ D1 (M=128, N=8, K=128). A-frag = W2 rows
//    16wv..16wv+15 preloaded (16 u32/lane, REPLACES w2h[32]); B-frag = 4x
//    ds_read_b128 from [dir][row] sD1 (zero-padded to 16 dirs); 4x
//    mfma_f32_16x16x32_f16; dp2 scale via new sDp2[128].
//  * B reuses the same A-frag, N=1 (B cols 1-15 zero): 4 MFMAs; cn==0 lanes
//    apply lipswish, write sH2 + sDp2.
//  * A, C, D, F, cJ build: byte-identical to R12.
// Frag layout (16x16x32 f16): A[m][k]: m=lane&15, k=(lane>>4)*8+e; B[k][n]:
// n=lane&15, same k; D: col(N)=lane&15, row(M)=(lane>>4)*4+reg [guide-verified].
#define NBATCH 32
#define LPATH  513
#define NWIN   32
#define LSIG   36
#define DSTR   136   // [dir] stride sD1/sD2 (f16) = 17 uint4
#define FSTR   72    // [dir] stride sFh (f16) = 9 uint4

typedef unsigned int u32;
typedef _Float16 h2 __attribute__((ext_vector_type(2)));
typedef _Float16 f16x8 __attribute__((ext_vector_type(8)));
typedef float f32x4 __attribute__((ext_vector_type(4)));

__device__ __forceinline__ u32 pkh(float a, float b){
  return __builtin_bit_cast(u32, __builtin_amdgcn_cvt_pkrtz(a, b));
}
__device__ __forceinline__ float dot2(u32 a, u32 b, float c){
#if __has_builtin(__builtin_amdgcn_fdot2)
  return __builtin_amdgcn_fdot2(__builtin_bit_cast(h2,a),
                                __builtin_bit_cast(h2,b), c, false);
#else
  h2 x = __builtin_bit_cast(h2,a), y = __builtin_bit_cast(h2,b);
  return c + (float)x[0]*(float)y[0] + (float)x[1]*(float)y[1];
#endif
}
__device__ __forceinline__ float tanh_fast(float x){
  float e = __expf(2.f*x);
  return 1.f - 2.f/(e+1.f);
}

// DPP cross-lane adds: VALU-only, no LDS-pipe traffic.
#define DPP_XOR1 0xB1   // quad_perm [1,0,3,2]
#define DPP_XOR2 0x4E   // quad_perm [2,3,0,1]
#define DPP_ROR8 0x128  // row_ror:8 == lane^8 within each 16-lane row
#define DPP_HMIR 0x141  // row_half_mirror == lane^7 within each 8-lane half
template<int CTRL>
__device__ __forceinline__ float dppadd(float x){
  int v = __builtin_amdgcn_update_dpp(0, __builtin_bit_cast(int,x),
                                      CTRL, 0xF, 0xF, false);
  return x + __builtin_bit_cast(float, v);
}

extern "C" __global__ __launch_bounds__(512, 1)
void cde_kernel(const float* __restrict__ cv,
                const float* __restrict__ Wi1g, const float* __restrict__ bi1g,
                const float* __restrict__ Wi2g, const float* __restrict__ bi2g,
                const float* __restrict__ W1g,  const float* __restrict__ b1g,
                const float* __restrict__ W2g,  const float* __restrict__ b2g,
                const float* __restrict__ W3g,  const float* __restrict__ b3g,
                const float* __restrict__ Wrg,  const float* __restrict__ brg,
                const float* __restrict__ shg,
                float* __restrict__ outp)
{
  // ---- LDS (~16 KB) ----
  __shared__ __align__(16) float sG[NWIN*LSIG];
  __shared__ __align__(16) float sWr[256];
  __shared__ float sBr[4], sSh[1];
  __shared__ __align__(16) float sY[64];
  __shared__ float sK1[64], sLw[64];
  __shared__ float sB2[128];                   // b2 per row (B rows != t-row)
  __shared__ float sDp2[128];                  // dp2 per row (B -> E)
  __shared__ __align__(16) _Float16 sYinp[64];
  __shared__ __align__(16) _Float16 sH1[128];
  __shared__ __align__(16) _Float16 sH2[128];
  __shared__ __align__(16) _Float16 sFh[8*FSTR];
  __shared__ __align__(16) _Float16 sD1[16*DSTR];  // dirs 8-15 zero-padded
  __shared__ __align__(16) _Float16 sD2[8*DSTR];

  const int t  = threadIdx.x;        // 0..511
  const int b  = blockIdx.x;
  const int wv = t >> 6;             // wave id 0..7 (MFMA M-tile)
  const int l  = t & 63;             // lane id
  const int cn = l & 15;             // MFMA N-lane (col)
  const int kg = l >> 4;             // MFMA K-group
  const int r  = t >> 2;             // 0..127 (A/D row)
  const int m  = t & 1;              // col half
  const int g  = (t >> 1) & 1;       // dir group (D)
  const int hb = (t >> 3) & 1;       // bit3: pair K-slice selector (A/D)
  const int i8 = t & 7;              // dir (C/F row-block)
  const int a8 = t >> 3;             // 0..63 (C/F col within block)
  const int p  = i8*64 + a8;         // owned W3 row
  const int pE = i8*64 + (a8 & ~1);  // C/F pair's even row
  const int pO = i8*64 + (a8 |  1);  // C/F pair's odd row
  const int rE = r & ~2;             // A/D pair's even row
  const int rO = r |  2;             // A/D pair's odd row

  // ---- init readout consts + zero-pad sD1 dirs 8-15 (stay zero forever) ----
  if (t < 256) sWr[t] = Wrg[t];
  if (t < 4)   sBr[t] = brg[t];
  if (t == 0)  sSh[0] = shg[0];
  if (t < 128) sB2[t] = b2g[t];
  for (int z = t; z < 8*DSTR; z += 512) sD1[8*DSTR + z] = (_Float16)0.f;

  // ---- depth-2 Lyndon log-signatures, one window per thread (t<32) ----
  if (t < NWIN){
    const float4* cv4 = (const float4*)cv;
    const int base = (b*LPATH + t*16)*2;
    float cur[8], pre[8], acc[8], lvw[28];
    { float4 a = cv4[base], d = cv4[base+1];
      cur[0]=a.x;cur[1]=a.y;cur[2]=a.z;cur[3]=a.w;
      cur[4]=d.x;cur[5]=d.y;cur[6]=d.z;cur[7]=d.w; }
    #pragma unroll
    for (int d=0; d<8; d++){ pre[d]=0.f; acc[d]=0.f; }
    #pragma unroll
    for (int pq=0; pq<28; pq++) lvw[pq]=0.f;
    for (int w=1; w<=16; w++){
      float nxt[8], inc[8];
      { float4 a = cv4[base+2*w], d = cv4[base+2*w+1];
        nxt[0]=a.x;nxt[1]=a.y;nxt[2]=a.z;nxt[3]=a.w;
        nxt[4]=d.x;nxt[5]=d.y;nxt[6]=d.z;nxt[7]=d.w; }
      #pragma unroll
      for (int d=0; d<8; d++) inc[d] = nxt[d]-cur[d];
      int pq=0;
      #pragma unroll
      for (int i=0; i<8; i++)
        #pragma unroll
        for (int j2=i+1; j2<8; j2++){ lvw[pq] += pre[i]*inc[j2] - pre[j2]*inc[i]; pq++; }
      #pragma unroll
      for (int d=0; d<8; d++){ acc[d]+=inc[d]; pre[d]+=inc[d]; cur[d]=nxt[d]; }
    }
    float* gd = &sG[t*LSIG];
    #pragma unroll
    for (int d=0; d<8; d++) gd[d] = acc[d];
    #pragma unroll
    for (int pq=0; pq<28; pq++) gd[8+pq] = 0.5f*lvw[pq];
  }

  // ---- y0 = Wi2 @ lipswish(Wi1 @ x0 + bi1) + bi2 ----
  if (t < 64){
    float z = bi1g[t];
    #pragma unroll
    for (int d=0; d<8; d++) z += Wi1g[t*8+d] * cv[(b*LPATH)*8 + d];
    float s = 1.f/(1.f+__expf(-z));
    sLw[t] = 0.909f*z*s;
  }
  __syncthreads();
  if (t < 64){
    float z = bi2g[t];
    #pragma unroll 8
    for (int k=0; k<64; k++) z += Wi2g[t*64+k] * sLw[k];
    sY[t] = z;
    sYinp[t] = (_Float16)z;
  }
  __syncthreads();
  if (t < 4){
    float z = sBr[t] + sSh[0];
    #pragma unroll 8
    for (int a=0; a<64; a++) z += sWr[t*64+a]*sY[a];
    outp[(b*33 + 0)*4 + t] = z;
  }

  // ---- per-thread weight registers ----
  // w1h: pair-rows rE/rO, (m,hb) K-slice           -> A and D (R12 layout).
  // w2f: MFMA A-frag, W2[16wv+cn][k=32c+kg*8+e]    -> B and E (replaces w2h).
  // w3e/w3o: K-half (a8&1) of rows pE/pO           -> C and F (pair-split).
  u32 w1h[16], w3e[32], w3o[32];
  f16x8 w2f[4];
  {
    const float2* W1f2 = (const float2*)W1g;
    #pragma unroll
    for (int i=0; i<8; i++){ float2 v = W1f2[rE*32 + m*16 + hb*8 + i]; w1h[i]   = pkh(v.x, v.y); }
    #pragma unroll
    for (int i=0; i<8; i++){ float2 v = W1f2[rO*32 + m*16 + hb*8 + i]; w1h[8+i] = pkh(v.x, v.y); }
    const float2* W2f2 = (const float2*)W2g;
    #pragma unroll
    for (int c=0; c<4; c++){
      uint4 tv;
      float2 v0 = W2f2[(16*wv + cn)*64 + 16*c + kg*4 + 0];
      float2 v1 = W2f2[(16*wv + cn)*64 + 16*c + kg*4 + 1];
      float2 v2 = W2f2[(16*wv + cn)*64 + 16*c + kg*4 + 2];
      float2 v3 = W2f2[(16*wv + cn)*64 + 16*c + kg*4 + 3];
      tv.x = pkh(v0.x, v0.y); tv.y = pkh(v1.x, v1.y);
      tv.z = pkh(v2.x, v2.y); tv.w = pkh(v3.x, v3.y);
      w2f[c] = __builtin_bit_cast(f16x8, tv);
    }
    const float4* W3f4 = (const float4*)W3g;
    #pragma unroll
    for (int k=0; k<16; k++){
      float4 v = W3f4[pE*32 + (a8&1)*16 + k];
      w3e[2*k]   = pkh(v.x, v.y);
      w3e[2*k+1] = pkh(v.z, v.w);
    }
    #pragma unroll
    for (int k=0; k<16; k++){
      float4 v = W3f4[pO*32 + (a8&1)*16 + k];
      w3o[2*k]   = pkh(v.x, v.y);
      w3o[2*k+1] = pkh(v.z, v.w);
    }
  }
  const float b1r = b1g[r], b3r = b3g[p];

  float gi = 0.f;       // gcur[i8], per window
  float cJ[4][4];       // C[j(q)][4g+k], per window (R12 build)

  // One vector-field eval. mode 0: k1 (sK1, sYinp=y+k1, fused readout in A).
  // mode 1: k2 (Heun update fused in F).
  auto EVAL = [&](int mode, int s){
    __syncthreads();                          // sYinp (and sY) ready
    float dp1, fr;
    // ---- A: h1 = lipswish(W1 y + b1); pair rows, (m,hb) slice (R12) ----
    {
      if (mode == 0 && s > 0 && t >= 504 && t < 508){
        int o = t - 504;
        float z = sBr[o] + sSh[0];
        const float4* wr4 = (const float4*)&sWr[o*64];
        const float4* y4f = (const float4*)sY;
        #pragma unroll
        for (int q=0; q<16; q++){
          float4 w = wr4[q], y = y4f[q];
          z += w.x*y.x + w.y*y.y + w.z*y.z + w.w*y.w;
        }
        outp[(b*33 + s)*4 + o] = z;
      }
      const uint4* y4 = (const uint4*)sYinp;
      const int qa = m*4 + hb*2;
      uint4 A0 = y4[qa], A1 = y4[qa+1];
      float e0 = dot2(w1h[0], A0.x, 0.f), e1 = dot2(w1h[1], A0.y, 0.f);
      e0 = dot2(w1h[2], A0.z, e0); e1 = dot2(w1h[3], A0.w, e1);
      e0 = dot2(w1h[4], A1.x, e0); e1 = dot2(w1h[5], A1.y, e1);
      e0 = dot2(w1h[6], A1.z, e0); e1 = dot2(w1h[7], A1.w, e1);
      float o0 = dot2(w1h[8],  A0.x, 0.f), o1 = dot2(w1h[9],  A0.y, 0.f);
      o0 = dot2(w1h[10], A0.z, o0); o1 = dot2(w1h[11], A0.w, o1);
      o0 = dot2(w1h[12], A1.x, o0); o1 = dot2(w1h[13], A1.y, o1);
      o0 = dot2(w1h[14], A1.z, o0); o1 = dot2(w1h[15], A1.w, o1);
      float zE = dppadd<DPP_ROR8>(e0+e1);
      float zO = dppadd<DPP_ROR8>(o0+o1);
      zE = dppadd<DPP_XOR1>(zE);
      zO = dppadd<DPP_XOR1>(zO);
      float z = (hb ? zO : zE) + b1r;
      float sg = 1.f/(1.f+__expf(-z));
      dp1 = 0.909f*sg*(1.f + z*(1.f-sg));
      if ((t & 3) == 0) sH1[r] = (_Float16)(0.909f*z*sg);
    }
    __syncthreads();
    // ---- B (MFMA, N=1): z2 = W2 @ h1; lipswish rows on cn==0 lanes ----
    {
      f32x4 acc = {0.f, 0.f, 0.f, 0.f};
      #pragma unroll
      for (int c=0; c<4; c++){
        f16x8 bf = {};
        if (cn == 0) bf = *(const f16x8*)&sH1[32*c + kg*8];
        acc = __builtin_amdgcn_mfma_f32_16x16x32_f16(w2f[c], bf, acc, 0, 0, 0);
      }
      if (cn == 0){
        #pragma unroll
        for (int j=0; j<4; j++){
          const int row = 16*wv + kg*4 + j;
          float z = acc[j] + sB2[row];
          float sg = 1.f/(1.f+__expf(-z));
          sH2[row]  = (_Float16)(0.909f*z*sg);
          sDp2[row] = 0.909f*sg*(1.f + z*(1.f-sg));
        }
      }
    }
    __syncthreads();
    // ---- C: f = tanh(W3 h2 + b3); pair-split K-halves (R12) ----
    {
      const uint4* h4 = (const uint4*)sH2;
      float e0=0.f, e1=0.f, o0=0.f, o1=0.f;
      #pragma unroll
      for (int q=0; q<8; q++){
        uint4 hv = h4[(a8&1)*8 + q];          // own K-half only (8 uint4)
        e0 = dot2(w3e[4*q+0], hv.x, e0); e1 = dot2(w3e[4*q+1], hv.y, e1);
        e0 = dot2(w3e[4*q+2], hv.z, e0); e1 = dot2(w3e[4*q+3], hv.w, e1);
        o0 = dot2(w3o[4*q+0], hv.x, o0); o1 = dot2(w3o[4*q+1], hv.y, o1);
        o0 = dot2(w3o[4*q+2], hv.z, o0); o1 = dot2(w3o[4*q+3], hv.w, o1);
      }
      float se = dppadd<DPP_ROR8>(e0+e1);     // + partner's other-half partial
      float so = dppadd<DPP_ROR8>(o0+o1);
      fr = tanh_fast(((a8&1) ? so : se) + b3r);
      sFh[i8*FSTR + a8] = (_Float16)fr;
    }
    __syncthreads();
    // ---- D: P_i = W1 @ f_i ; D1_j = dp1 * sum_i C[j,i] P_i (R12) ----
    {
      const uint4* f4 = (const uint4*)sFh;
      float P[4];
      #pragma unroll
      for (int k=0; k<4; k++){
        const uint4* fd = &f4[(4*g + k)*9 + m*4 + hb*2];
        uint4 A0 = fd[0], A1 = fd[1];
        float e0 = dot2(w1h[0], A0.x, 0.f), e1 = dot2(w1h[1], A0.y, 0.f);
        e0 = dot2(w1h[2], A0.z, e0); e1 = dot2(w1h[3], A0.w, e1);
        e0 = dot2(w1h[4], A1.x, e0); e1 = dot2(w1h[5], A1.y, e1);
        e0 = dot2(w1h[6], A1.z, e0); e1 = dot2(w1h[7], A1.w, e1);
        float o0 = dot2(w1h[8],  A0.x, 0.f), o1 = dot2(w1h[9],  A0.y, 0.f);
        o0 = dot2(w1h[10], A0.z, o0); o1 = dot2(w1h[11], A0.w, o1);
        o0 = dot2(w1h[12], A1.x, o0); o1 = dot2(w1h[13], A1.y, o1);
        o0 = dot2(w1h[14], A1.z, o0); o1 = dot2(w1h[15], A1.w, o1);
        float pe = dppadd<DPP_ROR8>(e0+e1);
        float po = dppadd<DPP_ROR8>(o0+o1);
        pe = dppadd<DPP_XOR1>(pe);
        po = dppadd<DPP_XOR1>(po);
        P[k] = hb ? po : pe;                  // P_dir[r], own row
      }
      #pragma unroll
      for (int q=0; q<4; q++){
        float pj = cJ[q][0]*P[0] + cJ[q][1]*P[1] + cJ[q][2]*P[2] + cJ[q][3]*P[3];
        pj = dppadd<DPP_XOR2>(pj);            // + other dir-group's partial
        if ((q >> 1) == g){
          int j = 2*m + (q & 1) + (q >> 1)*4;
          sD1[j*DSTR + r] = (_Float16)(dp1*pj);
        }
      }
    }
    __syncthreads();
    // ---- E (MFMA): D2 = dp2 .* (W2 @ D1), M=128 N=8(16 padded) K=128 ----
    {
      f32x4 acc = {0.f, 0.f, 0.f, 0.f};
      #pragma unroll
      for (int c=0; c<4; c++){
        f16x8 bf = *(const f16x8*)&sD1[cn*DSTR + 32*c + kg*8];
        acc = __builtin_amdgcn_mfma_f32_16x16x32_f16(w2f[c], bf, acc, 0, 0, 0);
      }
      if (cn < 8){
        #pragma unroll
        for (int j=0; j<4; j++){
          const int row = 16*wv + kg*4 + j;
          sD2[cn*DSTR + row] = (_Float16)(sDp2[row]*acc[j]);
        }
      }
    }
    __syncthreads();
    // ---- F: con = g_i*f + (1-f^2)*(W3 D2_i); k-sum all-DPP; Heun fused ----
    {
      const uint4* d4 = (const uint4*)&sD2[i8*DSTR];
      float e0=0.f, e1=0.f, o0=0.f, o1=0.f;
      #pragma unroll
      for (int q=0; q<8; q++){
        uint4 dv = d4[(a8&1)*8 + q];          // own K-half of D2[i8]
        e0 = dot2(w3e[4*q+0], dv.x, e0); e1 = dot2(w3e[4*q+1], dv.y, e1);
        e0 = dot2(w3e[4*q+2], dv.z, e0); e1 = dot2(w3e[4*q+3], dv.w, e1);
        o0 = dot2(w3o[4*q+0], dv.x, o0); o1 = dot2(w3o[4*q+1], dv.y, o1);
        o0 = dot2(w3o[4*q+2], dv.z, o0); o1 = dot2(w3o[4*q+3], dv.w, o1);
      }
      float ze = dppadd<DPP_ROR8>(e0+e1);
      float zo = dppadd<DPP_ROR8>(o0+o1);
      float z  = (a8&1) ? zo : ze;
      float con = gi*fr + (1.f - fr*fr)*z;
      con = dppadd<DPP_XOR1>(con);            // i8 bit0
      con = dppadd<DPP_XOR2>(con);            // i8 bit1
      con = dppadd<DPP_HMIR>(con);            // i8 bit2 (quad uniform -> l^7 ok)
      if (i8 == 0){
        if (mode == 0){
          sK1[a8] = con;
          sYinp[a8] = (_Float16)(sY[a8] + con);   // midpoint input for eval2
        } else {
          float yn = sY[a8] + 0.5f*(sK1[a8] + con);
          sY[a8] = yn;
          sYinp[a8] = (_Float16)yn;
        }
      }
    }
  };

  // ---- main scan over windows ----
  for (int s = 0; s < NWIN; s++){
    const float* gcur = &sG[s*LSIG];
    gi = gcur[i8];
    // build cJ[q][k] = C[j(q)][4g+k], j(q) = 2m + (q&1) + (q>>1)*4 (R12).
    const float4* lv4 = (const float4*)(gcur + 8);    // 16B-aligned: 144s+32
    float4 L0=lv4[0],L1=lv4[1],L2=lv4[2],L3=lv4[3],L4=lv4[4],L5=lv4[5],L6=lv4[6];
    float lv[28] = {L0.x,L0.y,L0.z,L0.w, L1.x,L1.y,L1.z,L1.w,
                    L2.x,L2.y,L2.z,L2.w, L3.x,L3.y,L3.z,L3.w,
                    L4.x,L4.y,L4.z,L4.w, L5.x,L5.y,L5.z,L5.w,
                    L6.x,L6.y,L6.z,L6.w};
    #pragma unroll
    for (int q=0; q<4; q++){
      const int j0 = (q & 1) + (q >> 1)*4;    // m=0 candidate j
      const int j1 = j0 + 2;                  // m=1 candidate j
      #pragma unroll
      for (int k=0; k<4; k++){
        float v00, v01, v10, v11;             // v[m][g]
        { const int i = k;                    // g=0 dirs
          v00 = (i < j0) ?  lv[7*i - (i*(i-1))/2 + (j0-i-1)]
              : (i > j0) ? -lv[7*j0 - (j0*(j0-1))/2 + (i-j0-1)] : 0.f;
          v10 = (i < j1) ?  lv[7*i - (i*(i-1))/2 + (j1-i-1)]
              : (i > j1) ? -lv[7*j1 - (j1*(j1-1))/2 + (i-j1-1)] : 0.f; }
        { const int i = k + 4;                // g=1 dirs
          v01 = (i < j0) ?  lv[7*i - (i*(i-1))/2 + (j0-i-1)]
              : (i > j0) ? -lv[7*j0 - (j0*(j0-1))/2 + (i-j0-1)] : 0.f;
          v11 = (i < j1) ?  lv[7*i - (i*(i-1))/2 + (j1-i-1)]
              : (i > j1) ? -lv[7*j1 - (j1*(j1-1))/2 + (i-j1-1)] : 0.f; }
        float vm0 = g ? v01 : v00;
        float vm1 = g ? v11 : v10;
        cJ[q][k] = m ? vm1 : vm0;
      }
    }
    EVAL(0, s);
    EVAL(1, s);
  }
  __syncthreads();
  if (t < 4){                                 // final readout (y after win 31)
    float z = sBr[t] + sSh[0];
    #pragma unroll 8
    for (int a=0; a<64; a++) z += sWr[t*64+a]*sY[a];
    outp[(b*33 + 32)*4 + t] = z;
  }
}

extern "C" void kernel_launch(void* const* d_in, const int* in_sizes, int n_in,
                              void* d_out, int out_size, void* d_ws, size_t ws_size,
                              hipStream_t stream) {
  cde_kernel<<<dim3(NBATCH), dim3(512), 0, stream>>>(
      (const float*)d_in[0],
      (const float*)d_in[1],  (const float*)d_in[2],
      (const float*)d_in[3],  (const float*)d_in[4],
      (const float*)d_in[5],  (const float*)d_in[6],
      (const float*)d_in[7],  (const float*)d_in[8],
      (const float*)d_in[9],  (const float*)d_in[10],
      (const float*)d_in[11], (const float*)d_in[12],
      (const float*)d_in[13],
      (float*)d_out);
}